// Round 1
// baseline (1049.552 us; speedup 1.0000x reference)
//
#include <hip/hip_runtime.h>
#include <math.h>

// Problem constants (match reference setup_inputs)
#define BATCH 2
#define SEQ   2048
#define CDIM  1024
#define NH    16
#define HD    64
// M = BATCH*SEQ = 4096 rows for the projection GEMMs

// ---------------------------------------------------------------------------
// GEMM tiles: 128x128 macro-tile, K-step 32, 256 threads, 8x8 micro-tile.
// LDS tiles stored K-major (transposed) so inner loop reads are ds_read_b128.
// ---------------------------------------------------------------------------
#define TM 128
#define TN 128
#define TK 32
#define LDT (TM + 4)   // padded row stride (floats) for transposed tiles

// Fused QKV projection: out = x @ W^T + b for W in {Wq,Wk,Wv}.
// Grid: (M/TM, 3*CDIM/TN) = (32, 24). Writes q/k/v in [B,H,T,D] layout.
__global__ __launch_bounds__(256) void qkv_gemm(
    const float* __restrict__ x,
    const float* __restrict__ Wq, const float* __restrict__ bq,
    const float* __restrict__ Wk, const float* __restrict__ bk,
    const float* __restrict__ Wv, const float* __restrict__ bv,
    float* __restrict__ q, float* __restrict__ k, float* __restrict__ v)
{
    __shared__ float At[TK][LDT];
    __shared__ float Bt[TK][LDT];

    const int tid = threadIdx.x;
    const int tx = tid & 15;
    const int ty = tid >> 4;
    const int m0 = blockIdx.x * TM;
    const int nGlobal = blockIdx.y * TN;      // 0..3071
    const int w  = nGlobal >> 10;             // which weight
    const int n0 = nGlobal & 1023;            // col within that weight

    const float* W    = (w == 0) ? Wq : (w == 1) ? Wk : Wv;
    const float* bias = (w == 0) ? bq : (w == 1) ? bk : bv;
    float* dst        = (w == 0) ? q  : (w == 1) ? k  : v;

    float acc[8][8];
#pragma unroll
    for (int i = 0; i < 8; ++i)
#pragma unroll
        for (int j = 0; j < 8; ++j) acc[i][j] = 0.0f;

    for (int kt = 0; kt < CDIM; kt += TK) {
        // Load A tile (128 rows x 32 k), transpose into At[k][m]
#pragma unroll
        for (int l = 0; l < 4; ++l) {
            int lin = tid + l * 256;          // float4 index, 1024 total
            int r  = lin >> 3;                // 8 float4 per row
            int kk = (lin & 7) << 2;
            float4 val = *(const float4*)(x + (size_t)(m0 + r) * CDIM + kt + kk);
            At[kk + 0][r] = val.x;
            At[kk + 1][r] = val.y;
            At[kk + 2][r] = val.z;
            At[kk + 3][r] = val.w;
        }
        // Load B tile (W rows n0..n0+127 x 32 k), transpose into Bt[k][n]
#pragma unroll
        for (int l = 0; l < 4; ++l) {
            int lin = tid + l * 256;
            int r  = lin >> 3;
            int kk = (lin & 7) << 2;
            float4 val = *(const float4*)(W + (size_t)(n0 + r) * CDIM + kt + kk);
            Bt[kk + 0][r] = val.x;
            Bt[kk + 1][r] = val.y;
            Bt[kk + 2][r] = val.z;
            Bt[kk + 3][r] = val.w;
        }
        __syncthreads();
#pragma unroll
        for (int kk = 0; kk < TK; ++kk) {
            float4 a0 = *(float4*)&At[kk][ty * 8];
            float4 a1 = *(float4*)&At[kk][ty * 8 + 4];
            float4 b0 = *(float4*)&Bt[kk][tx * 8];
            float4 b1 = *(float4*)&Bt[kk][tx * 8 + 4];
            float a[8] = {a0.x, a0.y, a0.z, a0.w, a1.x, a1.y, a1.z, a1.w};
            float b[8] = {b0.x, b0.y, b0.z, b0.w, b1.x, b1.y, b1.z, b1.w};
#pragma unroll
            for (int i = 0; i < 8; ++i)
#pragma unroll
                for (int j = 0; j < 8; ++j)
                    acc[i][j] = fmaf(a[i], b[j], acc[i][j]);
        }
        __syncthreads();
    }

    // Epilogue: bias add, scatter to [B,H,T,D]
#pragma unroll
    for (int i = 0; i < 8; ++i) {
        int mrow = m0 + ty * 8 + i;
        int bb = mrow >> 11;          // / SEQ
        int t  = mrow & (SEQ - 1);
#pragma unroll
        for (int jj = 0; jj < 8; jj += 4) {
            int n = n0 + tx * 8 + jj; // within 0..1023
            int h = n >> 6;
            int d = n & 63;
            float4 val;
            val.x = acc[i][jj + 0] + bias[n + 0];
            val.y = acc[i][jj + 1] + bias[n + 1];
            val.z = acc[i][jj + 2] + bias[n + 2];
            val.w = acc[i][jj + 3] + bias[n + 3];
            *(float4*)(dst + ((size_t)(bb * NH + h) * SEQ + t) * HD + d) = val;
        }
    }
}

// Output projection: out = y @ Wp^T + bp. Grid: (32, 8).
__global__ __launch_bounds__(256) void proj_gemm(
    const float* __restrict__ y, const float* __restrict__ Wp,
    const float* __restrict__ bp, float* __restrict__ out)
{
    __shared__ float At[TK][LDT];
    __shared__ float Bt[TK][LDT];

    const int tid = threadIdx.x;
    const int tx = tid & 15;
    const int ty = tid >> 4;
    const int m0 = blockIdx.x * TM;
    const int n0 = blockIdx.y * TN;

    float acc[8][8];
#pragma unroll
    for (int i = 0; i < 8; ++i)
#pragma unroll
        for (int j = 0; j < 8; ++j) acc[i][j] = 0.0f;

    for (int kt = 0; kt < CDIM; kt += TK) {
#pragma unroll
        for (int l = 0; l < 4; ++l) {
            int lin = tid + l * 256;
            int r  = lin >> 3;
            int kk = (lin & 7) << 2;
            float4 val = *(const float4*)(y + (size_t)(m0 + r) * CDIM + kt + kk);
            At[kk + 0][r] = val.x;
            At[kk + 1][r] = val.y;
            At[kk + 2][r] = val.z;
            At[kk + 3][r] = val.w;
        }
#pragma unroll
        for (int l = 0; l < 4; ++l) {
            int lin = tid + l * 256;
            int r  = lin >> 3;
            int kk = (lin & 7) << 2;
            float4 val = *(const float4*)(Wp + (size_t)(n0 + r) * CDIM + kt + kk);
            Bt[kk + 0][r] = val.x;
            Bt[kk + 1][r] = val.y;
            Bt[kk + 2][r] = val.z;
            Bt[kk + 3][r] = val.w;
        }
        __syncthreads();
#pragma unroll
        for (int kk = 0; kk < TK; ++kk) {
            float4 a0 = *(float4*)&At[kk][ty * 8];
            float4 a1 = *(float4*)&At[kk][ty * 8 + 4];
            float4 b0 = *(float4*)&Bt[kk][tx * 8];
            float4 b1 = *(float4*)&Bt[kk][tx * 8 + 4];
            float a[8] = {a0.x, a0.y, a0.z, a0.w, a1.x, a1.y, a1.z, a1.w};
            float b[8] = {b0.x, b0.y, b0.z, b0.w, b1.x, b1.y, b1.z, b1.w};
#pragma unroll
            for (int i = 0; i < 8; ++i)
#pragma unroll
                for (int j = 0; j < 8; ++j)
                    acc[i][j] = fmaf(a[i], b[j], acc[i][j]);
        }
        __syncthreads();
    }

#pragma unroll
    for (int i = 0; i < 8; ++i) {
        int mrow = m0 + ty * 8 + i;
#pragma unroll
        for (int jj = 0; jj < 8; jj += 4) {
            int n = n0 + tx * 8 + jj;
            float4 val;
            val.x = acc[i][jj + 0] + bp[n + 0];
            val.y = acc[i][jj + 1] + bp[n + 1];
            val.z = acc[i][jj + 2] + bp[n + 2];
            val.w = acc[i][jj + 3] + bp[n + 3];
            *(float4*)(out + (size_t)mrow * CDIM + n) = val;
        }
    }
}

// ---------------------------------------------------------------------------
// Flash attention (causal), fp32. One block per (64-row q-tile, b*h).
// 256 threads as 16x16, 4x4 micro-tile over the 64x64 score tile.
// Online softmax; K-tile LDS buffer is reused for transposed P (fits 64KB).
// ---------------------------------------------------------------------------
__global__ __launch_bounds__(256) void attn_kernel(
    const float* __restrict__ q, const float* __restrict__ k,
    const float* __restrict__ v, float* __restrict__ y)
{
    __shared__ float Qt[HD][68];   // [d][r], Q pre-scaled by 1/sqrt(D)
    __shared__ float KP[64][68];   // phase A: Kt [d][c]; phase B: Pt [c][r]
    __shared__ float Vs[64][68];   // [c][d]

    const int tid = threadIdx.x;
    const int tx = tid & 15;
    const int ty = tid >> 4;
    const int qt = gridDim.x - 1 - blockIdx.x;   // heavy tiles first
    const int bh = blockIdx.y;                   // b*NH + h
    const int q0 = qt * 64;

    const float* qb = q + (size_t)bh * SEQ * HD;
    const float* kb = k + (size_t)bh * SEQ * HD;
    const float* vb = v + (size_t)bh * SEQ * HD;

    // Load Q tile transposed + pre-scaled
#pragma unroll
    for (int l = 0; l < 4; ++l) {
        int lin = tid + l * 256;       // float4 id, 1024 total
        int r  = lin >> 4;             // 16 float4 per 64-float row
        int d0 = (lin & 15) << 2;
        float4 val = *(const float4*)(qb + (size_t)(q0 + r) * HD + d0);
        Qt[d0 + 0][r] = val.x * 0.125f;
        Qt[d0 + 1][r] = val.y * 0.125f;
        Qt[d0 + 2][r] = val.z * 0.125f;
        Qt[d0 + 3][r] = val.w * 0.125f;
    }

    float o[4][4];
    float m_i[4], l_i[4];
#pragma unroll
    for (int i = 0; i < 4; ++i) {
        m_i[i] = -INFINITY;
        l_i[i] = 0.0f;
#pragma unroll
        for (int j = 0; j < 4; ++j) o[i][j] = 0.0f;
    }

    for (int kt = 0; kt <= qt; ++kt) {
        const int k0 = kt * 64;
        __syncthreads();   // previous PV done with KP(Pt)/Vs
        // Load K transposed into KP, V natural into Vs
#pragma unroll
        for (int l = 0; l < 4; ++l) {
            int lin = tid + l * 256;
            int r  = lin >> 4;
            int d0 = (lin & 15) << 2;
            float4 val = *(const float4*)(kb + (size_t)(k0 + r) * HD + d0);
            KP[d0 + 0][r] = val.x;
            KP[d0 + 1][r] = val.y;
            KP[d0 + 2][r] = val.z;
            KP[d0 + 3][r] = val.w;
        }
#pragma unroll
        for (int l = 0; l < 4; ++l) {
            int lin = tid + l * 256;
            int r  = lin >> 4;
            int d0 = (lin & 15) << 2;
            *(float4*)&Vs[r][d0] = *(const float4*)(vb + (size_t)(k0 + r) * HD + d0);
        }
        __syncthreads();

        // S = (Q*scale) K^T over this tile
        float s[4][4];
#pragma unroll
        for (int i = 0; i < 4; ++i)
#pragma unroll
            for (int j = 0; j < 4; ++j) s[i][j] = 0.0f;
#pragma unroll
        for (int d = 0; d < HD; ++d) {
            float4 a = *(float4*)&Qt[d][ty * 4];
            float4 b = *(float4*)&KP[d][tx * 4];
            float av[4] = {a.x, a.y, a.z, a.w};
            float bv[4] = {b.x, b.y, b.z, b.w};
#pragma unroll
            for (int i = 0; i < 4; ++i)
#pragma unroll
                for (int j = 0; j < 4; ++j)
                    s[i][j] = fmaf(av[i], bv[j], s[i][j]);
        }

        if (kt == qt) {   // causal mask on the diagonal tile
#pragma unroll
            for (int i = 0; i < 4; ++i)
#pragma unroll
                for (int j = 0; j < 4; ++j)
                    if (k0 + tx * 4 + j > q0 + ty * 4 + i) s[i][j] = -INFINITY;
        }

        __syncthreads();  // everyone done reading KP as Kt

        // Online softmax per row, then write P transposed into KP
#pragma unroll
        for (int i = 0; i < 4; ++i) {
            float mx = fmaxf(fmaxf(s[i][0], s[i][1]), fmaxf(s[i][2], s[i][3]));
            mx = fmaxf(mx, __shfl_xor(mx, 1, 16));
            mx = fmaxf(mx, __shfl_xor(mx, 2, 16));
            mx = fmaxf(mx, __shfl_xor(mx, 4, 16));
            mx = fmaxf(mx, __shfl_xor(mx, 8, 16));
            float newm = fmaxf(m_i[i], mx);
            float scale = __expf(m_i[i] - newm);   // 0 when m_i = -inf
            m_i[i] = newm;
            float rowsum = 0.0f;
#pragma unroll
            for (int j = 0; j < 4; ++j) {
                float p = __expf(s[i][j] - newm);  // masked -> 0
                s[i][j] = p;
                rowsum += p;
            }
            rowsum += __shfl_xor(rowsum, 1, 16);
            rowsum += __shfl_xor(rowsum, 2, 16);
            rowsum += __shfl_xor(rowsum, 4, 16);
            rowsum += __shfl_xor(rowsum, 8, 16);
            l_i[i] = l_i[i] * scale + rowsum;
#pragma unroll
            for (int j = 0; j < 4; ++j) o[i][j] *= scale;
        }
#pragma unroll
        for (int i = 0; i < 4; ++i)
#pragma unroll
            for (int j = 0; j < 4; ++j)
                KP[tx * 4 + j][ty * 4 + i] = s[i][j];   // Pt[c][r]

        __syncthreads();

        // O += P V
#pragma unroll
        for (int c = 0; c < 64; ++c) {
            float4 a = *(float4*)&KP[c][ty * 4];
            float4 b = *(float4*)&Vs[c][tx * 4];
            float av[4] = {a.x, a.y, a.z, a.w};
            float bv[4] = {b.x, b.y, b.z, b.w};
#pragma unroll
            for (int i = 0; i < 4; ++i)
#pragma unroll
                for (int j = 0; j < 4; ++j)
                    o[i][j] = fmaf(av[i], bv[j], o[i][j]);
        }
    }

    // Epilogue: normalize, store y in [B,T,C] layout
    const int bb = bh >> 4;
    const int h  = bh & 15;
#pragma unroll
    for (int i = 0; i < 4; ++i) {
        int t = q0 + ty * 4 + i;
        float inv = 1.0f / l_i[i];
        float4 val;
        val.x = o[i][0] * inv;
        val.y = o[i][1] * inv;
        val.z = o[i][2] * inv;
        val.w = o[i][3] * inv;
        *(float4*)(y + ((size_t)(bb * SEQ + t)) * CDIM + h * HD + tx * 4) = val;
    }
}

extern "C" void kernel_launch(void* const* d_in, const int* in_sizes, int n_in,
                              void* d_out, int out_size, void* d_ws, size_t ws_size,
                              hipStream_t stream) {
    const float* x  = (const float*)d_in[0];
    const float* Wq = (const float*)d_in[1];
    const float* bq = (const float*)d_in[2];
    const float* Wk = (const float*)d_in[3];
    const float* bk = (const float*)d_in[4];
    const float* Wv = (const float*)d_in[5];
    const float* bv = (const float*)d_in[6];
    const float* Wp = (const float*)d_in[7];
    const float* bp = (const float*)d_in[8];
    float* out = (float*)d_out;

    const size_t S = (size_t)BATCH * SEQ * CDIM;   // 4,194,304 floats
    float* qbuf = (float*)d_ws;
    float* kbuf = qbuf + S;
    float* vbuf = kbuf + S;
    float* ybuf = vbuf + S;                        // needs 64 MB total

    // 1) Fused QKV projection: M=4096, N=3*1024
    qkv_gemm<<<dim3(4096 / TM, (3 * CDIM) / TN), 256, 0, stream>>>(
        x, Wq, bq, Wk, bk, Wv, bv, qbuf, kbuf, vbuf);

    // 2) Causal flash attention
    attn_kernel<<<dim3(SEQ / 64, BATCH * NH), 256, 0, stream>>>(
        qbuf, kbuf, vbuf, ybuf);

    // 3) Output projection
    proj_gemm<<<dim3(4096 / TM, CDIM / TN), 256, 0, stream>>>(
        ybuf, Wp, bp, out);
}

// Round 5
// 283.862 us; speedup vs baseline: 3.6974x; 3.6974x over previous
//
#include <hip/hip_runtime.h>
#include <math.h>

#define BATCH 2
#define SEQ   2048
#define CDIM  1024
#define NH    16
#define HD    64

typedef _Float16 half8 __attribute__((ext_vector_type(8)));
typedef _Float16 half4 __attribute__((ext_vector_type(4)));
typedef float    f32x4 __attribute__((ext_vector_type(4)));

#define LDH 72   // padded LDS row stride in halves (144 B -> 4*row bank spread)

__device__ inline half8 cvt8(float4 a, float4 b) {
    half8 h;
    h[0] = (_Float16)a.x; h[1] = (_Float16)a.y; h[2] = (_Float16)a.z; h[3] = (_Float16)a.w;
    h[4] = (_Float16)b.x; h[5] = (_Float16)b.y; h[6] = (_Float16)b.z; h[7] = (_Float16)b.w;
    return h;
}

// ---------------------------------------------------------------------------
// Fused QKV projection, fp16 MFMA. Tile 128x128, BK=64, 4 waves (2x2),
// wave-tile 64x64 (4x4 fragments of 16x16x32). Writes q/k/v in [B,H,T,D].
// Fragment mapping (m89-verified): A: lane l -> row l&15, k (l>>4)*8+j;
// B: lane l -> col l&15, k (l>>4)*8+j; C/D: col l&15, row (l>>4)*4+reg.
// ---------------------------------------------------------------------------
__global__ __launch_bounds__(256) void qkv_gemm(
    const float* __restrict__ x,
    const float* __restrict__ Wq, const float* __restrict__ bq,
    const float* __restrict__ Wk, const float* __restrict__ bk,
    const float* __restrict__ Wv, const float* __restrict__ bv,
    float* __restrict__ q, float* __restrict__ k, float* __restrict__ v)
{
    __shared__ _Float16 Ash[128 * LDH];
    __shared__ _Float16 Bsh[128 * LDH];

    const int tid  = threadIdx.x;
    const int lane = tid & 63;
    const int wave = tid >> 6;
    const int wm = wave >> 1;
    const int wn = wave & 1;
    const int lg = lane >> 4;
    const int lr = lane & 15;

    const int m0 = blockIdx.x * 128;
    const int nG = blockIdx.y * 128;
    const int w  = nG >> 10;
    const int n0 = nG & 1023;

    const float* W    = (w == 0) ? Wq : (w == 1) ? Wk : Wv;
    const float* bias = (w == 0) ? bq : (w == 1) ? bk : bv;
    float* dst        = (w == 0) ? q  : (w == 1) ? k  : v;

    f32x4 acc[4][4];
#pragma unroll
    for (int m = 0; m < 4; ++m)
#pragma unroll
        for (int n = 0; n < 4; ++n) acc[m][n] = (f32x4)0.0f;

    for (int kt = 0; kt < CDIM; kt += 64) {
#pragma unroll
        for (int c = 0; c < 4; ++c) {
            int ch  = tid + c * 256;           // 1024 chunks of 8 floats
            int row = ch >> 3;
            int kc  = (ch & 7) * 8;
            const float* sa = x + (size_t)(m0 + row) * CDIM + kt + kc;
            float4 a0 = *(const float4*)sa;
            float4 a1 = *(const float4*)(sa + 4);
            *(half8*)&Ash[row * LDH + kc] = cvt8(a0, a1);
            const float* sb = W + (size_t)(n0 + row) * CDIM + kt + kc;
            float4 b0 = *(const float4*)sb;
            float4 b1 = *(const float4*)(sb + 4);
            *(half8*)&Bsh[row * LDH + kc] = cvt8(b0, b1);
        }
        __syncthreads();
#pragma unroll
        for (int kk = 0; kk < 2; ++kk) {
            half8 af[4], bf[4];
#pragma unroll
            for (int m = 0; m < 4; ++m)
                af[m] = *(half8*)&Ash[(wm * 64 + m * 16 + lr) * LDH + kk * 32 + lg * 8];
#pragma unroll
            for (int n = 0; n < 4; ++n)
                bf[n] = *(half8*)&Bsh[(wn * 64 + n * 16 + lr) * LDH + kk * 32 + lg * 8];
#pragma unroll
            for (int m = 0; m < 4; ++m)
#pragma unroll
                for (int n = 0; n < 4; ++n)
                    acc[m][n] = __builtin_amdgcn_mfma_f32_16x16x32_f16(af[m], bf[n], acc[m][n], 0, 0, 0);
        }
        __syncthreads();
    }

#pragma unroll
    for (int n = 0; n < 4; ++n) {
        int col = n0 + wn * 64 + n * 16 + lr;
        float bv_ = bias[col];
        int h = col >> 6, d = col & 63;
#pragma unroll
        for (int m = 0; m < 4; ++m) {
#pragma unroll
            for (int i = 0; i < 4; ++i) {
                int mr = m0 + wm * 64 + m * 16 + lg * 4 + i;
                int bb = mr >> 11;
                int t  = mr & (SEQ - 1);
                dst[((size_t)(bb * NH + h) * SEQ + t) * HD + d] = acc[m][n][i] + bv_;
            }
        }
    }
}

// ---------------------------------------------------------------------------
// Output projection, fp16 MFMA. Tile 128x64, BK=64, 4 waves (2x2),
// wave-tile 64x32 (4x2 fragments). Grid (32,16) = 512 blocks (2/CU).
// ---------------------------------------------------------------------------
__global__ __launch_bounds__(256) void proj_gemm(
    const float* __restrict__ y, const float* __restrict__ Wp,
    const float* __restrict__ bp, float* __restrict__ out)
{
    __shared__ _Float16 Ash[128 * LDH];
    __shared__ _Float16 Bsh[64 * LDH];

    const int tid  = threadIdx.x;
    const int lane = tid & 63;
    const int wave = tid >> 6;
    const int wm = wave >> 1;
    const int wn = wave & 1;
    const int lg = lane >> 4;
    const int lr = lane & 15;

    const int m0 = blockIdx.x * 128;
    const int n0 = blockIdx.y * 64;

    f32x4 acc[4][2];
#pragma unroll
    for (int m = 0; m < 4; ++m)
#pragma unroll
        for (int n = 0; n < 2; ++n) acc[m][n] = (f32x4)0.0f;

    for (int kt = 0; kt < CDIM; kt += 64) {
#pragma unroll
        for (int c = 0; c < 4; ++c) {
            int ch  = tid + c * 256;
            int row = ch >> 3;
            int kc  = (ch & 7) * 8;
            const float* sa = y + (size_t)(m0 + row) * CDIM + kt + kc;
            float4 a0 = *(const float4*)sa;
            float4 a1 = *(const float4*)(sa + 4);
            *(half8*)&Ash[row * LDH + kc] = cvt8(a0, a1);
        }
#pragma unroll
        for (int c = 0; c < 2; ++c) {
            int ch  = tid + c * 256;           // 512 chunks for 64 rows
            int row = ch >> 3;
            int kc  = (ch & 7) * 8;
            const float* sb = Wp + (size_t)(n0 + row) * CDIM + kt + kc;
            float4 b0 = *(const float4*)sb;
            float4 b1 = *(const float4*)(sb + 4);
            *(half8*)&Bsh[row * LDH + kc] = cvt8(b0, b1);
        }
        __syncthreads();
#pragma unroll
        for (int kk = 0; kk < 2; ++kk) {
            half8 af[4], bf[2];
#pragma unroll
            for (int m = 0; m < 4; ++m)
                af[m] = *(half8*)&Ash[(wm * 64 + m * 16 + lr) * LDH + kk * 32 + lg * 8];
#pragma unroll
            for (int n = 0; n < 2; ++n)
                bf[n] = *(half8*)&Bsh[(wn * 32 + n * 16 + lr) * LDH + kk * 32 + lg * 8];
#pragma unroll
            for (int m = 0; m < 4; ++m)
#pragma unroll
                for (int n = 0; n < 2; ++n)
                    acc[m][n] = __builtin_amdgcn_mfma_f32_16x16x32_f16(af[m], bf[n], acc[m][n], 0, 0, 0);
        }
        __syncthreads();
    }

#pragma unroll
    for (int n = 0; n < 2; ++n) {
        int col = n0 + wn * 32 + n * 16 + lr;
        float bv_ = bp[col];
#pragma unroll
        for (int m = 0; m < 4; ++m) {
#pragma unroll
            for (int i = 0; i < 4; ++i) {
                int mr = m0 + wm * 64 + m * 16 + lg * 4 + i;
                out[(size_t)mr * CDIM + col] = acc[m][n][i] + bv_;
            }
        }
    }
}

// ---------------------------------------------------------------------------
// Flash attention (causal), fp16 MFMA, swapped operands.
// S^T = mfma(A=K, B=Q^T)  -> lane holds (kv=(l>>4)*4+i, q=l&15)
// O^T = mfma(A=V^T, B=P^T) -> contiguous LDS reads for both operands.
// QBLK=128 (wave owns 32 q-rows), KBLK=64. Q pre-scaled, in registers.
// ---------------------------------------------------------------------------
__global__ __launch_bounds__(256) void attn_kernel(
    const float* __restrict__ q, const float* __restrict__ k,
    const float* __restrict__ v, float* __restrict__ y)
{
    __shared__ _Float16 Kt[64 * LDH];        // [kv][d] natural
    __shared__ _Float16 Vt[64 * LDH];        // [d][kv] transposed
    __shared__ _Float16 Pt[4][32 * LDH];     // per-wave [q][kv]

    const int tid  = threadIdx.x;
    const int lane = tid & 63;
    const int wave = tid >> 6;
    const int lg = lane >> 4;
    const int lr = lane & 15;

    const int qt  = gridDim.x - 1 - blockIdx.x;   // heavy tiles first
    const int bh  = blockIdx.y;
    const int q0  = qt * 128;
    const int q0w = q0 + wave * 32;

    const float* qb = q + (size_t)bh * SEQ * HD;
    const float* kb = k + (size_t)bh * SEQ * HD;
    const float* vb = v + (size_t)bh * SEQ * HD;

    // Preload Q fragments (B-operand layout), scaled by 1/sqrt(D)
    half8 qfr[2][2];
#pragma unroll
    for (int f = 0; f < 2; ++f) {
#pragma unroll
        for (int kk = 0; kk < 2; ++kk) {
            const float* s = qb + (size_t)(q0w + f * 16 + lr) * HD + kk * 32 + lg * 8;
            float4 u0 = *(const float4*)s;
            float4 u1 = *(const float4*)(s + 4);
            u0.x *= 0.125f; u0.y *= 0.125f; u0.z *= 0.125f; u0.w *= 0.125f;
            u1.x *= 0.125f; u1.y *= 0.125f; u1.z *= 0.125f; u1.w *= 0.125f;
            qfr[f][kk] = cvt8(u0, u1);
        }
    }

    f32x4 ot[4][2];                       // O^T [d-frag][q-frag]
#pragma unroll
    for (int df = 0; df < 4; ++df)
#pragma unroll
        for (int qf = 0; qf < 2; ++qf) ot[df][qf] = (f32x4)0.0f;
    float m_i[2] = {-INFINITY, -INFINITY};
    float l_i[2] = {0.0f, 0.0f};

    const int ntiles = 2 * qt + 2;
    for (int kt = 0; kt < ntiles; ++kt) {
        const int k0 = kt * 64;
        __syncthreads();                  // protect Kt/Vt from prior reads
        // Stage K [kv][d]
#pragma unroll
        for (int c = 0; c < 2; ++c) {
            int ch  = tid + c * 256;      // 512 chunks of 8 floats
            int row = ch >> 3;
            int kc  = (ch & 7) * 8;
            const float* s = kb + (size_t)(k0 + row) * HD + kc;
            float4 u0 = *(const float4*)s;
            float4 u1 = *(const float4*)(s + 4);
            *(half8*)&Kt[row * LDH + kc] = cvt8(u0, u1);
        }
        // Stage V transposed [d][kv] via 4x4 register blocks
        {
            int kv0 = (tid & 15) * 4;
            int d0  = (tid >> 4) * 4;
            float4 r0 = *(const float4*)(vb + (size_t)(k0 + kv0 + 0) * HD + d0);
            float4 r1 = *(const float4*)(vb + (size_t)(k0 + kv0 + 1) * HD + d0);
            float4 r2 = *(const float4*)(vb + (size_t)(k0 + kv0 + 2) * HD + d0);
            float4 r3 = *(const float4*)(vb + (size_t)(k0 + kv0 + 3) * HD + d0);
            half4 c;
            c[0] = (_Float16)r0.x; c[1] = (_Float16)r1.x; c[2] = (_Float16)r2.x; c[3] = (_Float16)r3.x;
            *(half4*)&Vt[(d0 + 0) * LDH + kv0] = c;
            c[0] = (_Float16)r0.y; c[1] = (_Float16)r1.y; c[2] = (_Float16)r2.y; c[3] = (_Float16)r3.y;
            *(half4*)&Vt[(d0 + 1) * LDH + kv0] = c;
            c[0] = (_Float16)r0.z; c[1] = (_Float16)r1.z; c[2] = (_Float16)r2.z; c[3] = (_Float16)r3.z;
            *(half4*)&Vt[(d0 + 2) * LDH + kv0] = c;
            c[0] = (_Float16)r0.w; c[1] = (_Float16)r1.w; c[2] = (_Float16)r2.w; c[3] = (_Float16)r3.w;
            *(half4*)&Vt[(d0 + 3) * LDH + kv0] = c;
        }
        __syncthreads();

        // S^T = K · Q^T
        f32x4 st[4][2];
#pragma unroll
        for (int mf = 0; mf < 4; ++mf)
#pragma unroll
            for (int qf = 0; qf < 2; ++qf) st[mf][qf] = (f32x4)0.0f;
#pragma unroll
        for (int kk = 0; kk < 2; ++kk) {
#pragma unroll
            for (int mf = 0; mf < 4; ++mf) {
                half8 ak = *(half8*)&Kt[(mf * 16 + lr) * LDH + kk * 32 + lg * 8];
#pragma unroll
                for (int qf = 0; qf < 2; ++qf)
                    st[mf][qf] = __builtin_amdgcn_mfma_f32_16x16x32_f16(ak, qfr[qf][kk], st[mf][qf], 0, 0, 0);
            }
        }

        // Causal mask (wave-uniform guard)
        if (k0 + 63 > q0w) {
#pragma unroll
            for (int mf = 0; mf < 4; ++mf)
#pragma unroll
                for (int qf = 0; qf < 2; ++qf)
#pragma unroll
                    for (int i = 0; i < 4; ++i) {
                        int kv = k0 + mf * 16 + lg * 4 + i;
                        int qq = q0w + qf * 16 + lr;
                        if (kv > qq) st[mf][qf][i] = -INFINITY;
                    }
        }

        // Online softmax (2 q-states/thread) + P^T -> Pt[q][kv] as half4
#pragma unroll
        for (int qf = 0; qf < 2; ++qf) {
            float mx = -INFINITY;
#pragma unroll
            for (int mf = 0; mf < 4; ++mf)
#pragma unroll
                for (int i = 0; i < 4; ++i) mx = fmaxf(mx, st[mf][qf][i]);
            mx = fmaxf(mx, __shfl_xor(mx, 16));
            mx = fmaxf(mx, __shfl_xor(mx, 32));
            float nm = fmaxf(m_i[qf], mx);
            float sc = __expf(m_i[qf] - nm);      // 0 on first finite tile
            m_i[qf] = nm;
            float rs = 0.0f;
#pragma unroll
            for (int mf = 0; mf < 4; ++mf) {
                half4 pk;
#pragma unroll
                for (int i = 0; i < 4; ++i) {
                    float p = __expf(st[mf][qf][i] - nm);
                    rs += p;
                    pk[i] = (_Float16)p;
                }
                *(half4*)&Pt[wave][(qf * 16 + lr) * LDH + mf * 16 + lg * 4] = pk;
            }
            rs += __shfl_xor(rs, 16);
            rs += __shfl_xor(rs, 32);
            l_i[qf] = l_i[qf] * sc + rs;
#pragma unroll
            for (int df = 0; df < 4; ++df)
#pragma unroll
                for (int i = 0; i < 4; ++i) ot[df][qf][i] *= sc;
        }

        // O^T += V^T · P^T
#pragma unroll
        for (int kk = 0; kk < 2; ++kk) {
            half8 bp_[2];
#pragma unroll
            for (int qf = 0; qf < 2; ++qf)
                bp_[qf] = *(half8*)&Pt[wave][(qf * 16 + lr) * LDH + kk * 32 + lg * 8];
#pragma unroll
            for (int df = 0; df < 4; ++df) {
                half8 av = *(half8*)&Vt[(df * 16 + lr) * LDH + kk * 32 + lg * 8];
#pragma unroll
                for (int qf = 0; qf < 2; ++qf)
                    ot[df][qf] = __builtin_amdgcn_mfma_f32_16x16x32_f16(av, bp_[qf], ot[df][qf], 0, 0, 0);
            }
        }
    }

    // Epilogue: normalize, store y in [B,T,C]
    const int bb = bh >> 4;
    const int h  = bh & 15;
#pragma unroll
    for (int qf = 0; qf < 2; ++qf) {
        float inv = 1.0f / l_i[qf];
        int t = q0w + qf * 16 + lr;
        float* dst = y + ((size_t)(bb * SEQ + t)) * CDIM + h * HD;
#pragma unroll
        for (int df = 0; df < 4; ++df)
#pragma unroll
            for (int i = 0; i < 4; ++i)
                dst[df * 16 + lg * 4 + i] = ot[df][qf][i] * inv;
    }
}

extern "C" void kernel_launch(void* const* d_in, const int* in_sizes, int n_in,
                              void* d_out, int out_size, void* d_ws, size_t ws_size,
                              hipStream_t stream) {
    const float* x  = (const float*)d_in[0];
    const float* Wq = (const float*)d_in[1];
    const float* bq = (const float*)d_in[2];
    const float* Wk = (const float*)d_in[3];
    const float* bk = (const float*)d_in[4];
    const float* Wv = (const float*)d_in[5];
    const float* bv = (const float*)d_in[6];
    const float* Wp = (const float*)d_in[7];
    const float* bp = (const float*)d_in[8];
    float* out = (float*)d_out;

    const size_t S = (size_t)BATCH * SEQ * CDIM;
    float* qbuf = (float*)d_ws;
    float* kbuf = qbuf + S;
    float* vbuf = kbuf + S;
    float* ybuf = vbuf + S;

    qkv_gemm<<<dim3(4096 / 128, 3072 / 128), 256, 0, stream>>>(
        x, Wq, bq, Wk, bk, Wv, bv, qbuf, kbuf, vbuf);

    attn_kernel<<<dim3(SEQ / 128, BATCH * NH), 256, 0, stream>>>(
        qbuf, kbuf, vbuf, ybuf);

    proj_gemm<<<dim3(4096 / 128, 1024 / 64), 256, 0, stream>>>(
        ybuf, Wp, bp, out);
}

// Round 8
// 243.512 us; speedup vs baseline: 4.3101x; 1.1657x over previous
//
#include <hip/hip_runtime.h>
#include <math.h>

#define BATCH 2
#define SEQ   2048
#define CDIM  1024
#define NH    16
#define HD    64

typedef _Float16 half8 __attribute__((ext_vector_type(8)));
typedef _Float16 half4 __attribute__((ext_vector_type(4)));
typedef float    f32x4 __attribute__((ext_vector_type(4)));

#define LDH 72   // padded stride (halves) for hand-staged LDS (Vt, Pt)

typedef const __attribute__((address_space(1))) void* gas_ptr;
typedef __attribute__((address_space(3))) void* las_ptr;

// Async global->LDS, 16B per lane: LDS dest = uniform base + lane*16,
// global src per-lane. (guide §5: m97 pattern, width=16)
__device__ __forceinline__ void gld16(const _Float16* g, _Float16* l) {
    __builtin_amdgcn_global_load_lds((gas_ptr)g, (las_ptr)l, 16, 0, 0);
}

__device__ inline half8 cvt8(float4 a, float4 b) {
    half8 h;
    h[0] = (_Float16)a.x; h[1] = (_Float16)a.y; h[2] = (_Float16)a.z; h[3] = (_Float16)a.w;
    h[4] = (_Float16)b.x; h[5] = (_Float16)b.y; h[6] = (_Float16)b.z; h[7] = (_Float16)b.w;
    return h;
}

// ---------------------------------------------------------------------------
// One-shot fp32 -> fp16 conversion of x, Wq|Wk|Wv (concat rows), Wp.
// 1,048,576 chunks of 8 floats; fully coalesced. ~48 MB traffic.
// ---------------------------------------------------------------------------
__global__ __launch_bounds__(256) void cvt_all(
    const float* __restrict__ x,
    const float* __restrict__ Wq, const float* __restrict__ Wk,
    const float* __restrict__ Wv, const float* __restrict__ Wp,
    _Float16* __restrict__ x16, _Float16* __restrict__ w16,
    _Float16* __restrict__ wp16)
{
    int c = blockIdx.x * 256 + threadIdx.x;
    const float* src;
    _Float16* dst;
    if (c < 524288) {                       // x: 4,194,304 floats
        src = x + (size_t)c * 8;
        dst = x16 + (size_t)c * 8;
    } else {
        int r = c - 524288;
        int w = r >> 17;                    // 131072 chunks per weight
        size_t off = (size_t)(r & 131071) * 8;
        if (w == 0)      { src = Wq + off; dst = w16 + off; }
        else if (w == 1) { src = Wk + off; dst = w16 + (1u << 20) + off; }
        else if (w == 2) { src = Wv + off; dst = w16 + (2u << 20) + off; }
        else             { src = Wp + off; dst = wp16 + off; }
    }
    float4 a = *(const float4*)src;
    float4 b = *(const float4*)(src + 4);
    *(half8*)dst = cvt8(a, b);
}

// ---------------------------------------------------------------------------
// Fused QKV projection, pure fp16, m97-style staging.
// Tile 128x128, BK=64, 4 waves (2x2), wave-tile 64x64.
// LDS tiles linear [row][64] halves; global_load_lds 16B (1KB/inst).
// Writes q/k/v fp16 in [B,H,T,D]; q pre-scaled by 1/sqrt(D).
// ---------------------------------------------------------------------------
__global__ __launch_bounds__(256) void qkv_gemm(
    const _Float16* __restrict__ x16, const _Float16* __restrict__ w16,
    const float* __restrict__ bq, const float* __restrict__ bk,
    const float* __restrict__ bv,
    _Float16* __restrict__ q, _Float16* __restrict__ k, _Float16* __restrict__ v)
{
    __shared__ _Float16 Ash[128 * 64];
    __shared__ _Float16 Bsh[128 * 64];

    const int tid  = threadIdx.x;
    const int lane = tid & 63;
    const int wave = tid >> 6;
    const int wm = wave >> 1;
    const int wn = wave & 1;
    const int lg = lane >> 4;
    const int lr = lane & 15;

    const int m0 = blockIdx.x * 128;
    const int nG = blockIdx.y * 128;
    const int w  = nG >> 10;

    const int srow = lane >> 3;          // row within 8-row chunk
    const int scol = (lane & 7) * 8;     // halves

    f32x4 acc[4][4];
#pragma unroll
    for (int m = 0; m < 4; ++m)
#pragma unroll
        for (int n = 0; n < 4; ++n) acc[m][n] = (f32x4)0.0f;

    for (int kt = 0; kt < CDIM; kt += 64) {
        __syncthreads();                 // prior reads of Ash/Bsh done
#pragma unroll
        for (int i = 0; i < 4; ++i) {
            int chunk = wave * 4 + i;    // 16 chunks x 1KB per tile
            int row = chunk * 8 + srow;
            gld16(x16 + (size_t)(m0 + row) * CDIM + kt + scol, Ash + chunk * 512);
            gld16(w16 + (size_t)(nG + row) * CDIM + kt + scol, Bsh + chunk * 512);
        }
        __syncthreads();                 // vmcnt(0)+barrier: tiles ready
#pragma unroll
        for (int kk = 0; kk < 2; ++kk) {
            half8 af[4], bf[4];
#pragma unroll
            for (int m = 0; m < 4; ++m)
                af[m] = *(half8*)&Ash[(wm * 64 + m * 16 + lr) * 64 + kk * 32 + lg * 8];
#pragma unroll
            for (int n = 0; n < 4; ++n)
                bf[n] = *(half8*)&Bsh[(wn * 64 + n * 16 + lr) * 64 + kk * 32 + lg * 8];
#pragma unroll
            for (int m = 0; m < 4; ++m)
#pragma unroll
                for (int n = 0; n < 4; ++n)
                    acc[m][n] = __builtin_amdgcn_mfma_f32_16x16x32_f16(af[m], bf[n], acc[m][n], 0, 0, 0);
        }
    }

    const float* bias = (w == 0) ? bq : (w == 1) ? bk : bv;
    _Float16* dst     = (w == 0) ? q  : (w == 1) ? k  : v;
    const float qs    = (w == 0) ? 0.125f : 1.0f;   // fold 1/sqrt(D) into q
    const int n0 = nG & 1023;

#pragma unroll
    for (int n = 0; n < 4; ++n) {
        int col = n0 + wn * 64 + n * 16 + lr;
        float bv_ = bias[col];
        int h = col >> 6, d = col & 63;
#pragma unroll
        for (int m = 0; m < 4; ++m) {
#pragma unroll
            for (int i = 0; i < 4; ++i) {
                int mr = m0 + wm * 64 + m * 16 + lg * 4 + i;
                int bb = mr >> 11;
                int t  = mr & (SEQ - 1);
                dst[((size_t)(bb * NH + h) * SEQ + t) * HD + d] =
                    (_Float16)((acc[m][n][i] + bv_) * qs);
            }
        }
    }
}

// ---------------------------------------------------------------------------
// Output projection: A = ybuf fp16 (gld16), B = wp16 (gld16), out fp32+bias.
// Tile 128x64, BK=64, 4 waves (2x2), wave-tile 64x32. Grid (32,16).
// ---------------------------------------------------------------------------
__global__ __launch_bounds__(256) void proj_gemm(
    const _Float16* __restrict__ y16, const _Float16* __restrict__ wp16,
    const float* __restrict__ bp, float* __restrict__ out)
{
    __shared__ _Float16 Ash[128 * 64];
    __shared__ _Float16 Bsh[64 * 64];

    const int tid  = threadIdx.x;
    const int lane = tid & 63;
    const int wave = tid >> 6;
    const int wm = wave >> 1;
    const int wn = wave & 1;
    const int lg = lane >> 4;
    const int lr = lane & 15;

    const int m0 = blockIdx.x * 128;
    const int n0 = blockIdx.y * 64;

    const int srow = lane >> 3;
    const int scol = (lane & 7) * 8;

    f32x4 acc[4][2];
#pragma unroll
    for (int m = 0; m < 4; ++m)
#pragma unroll
        for (int n = 0; n < 2; ++n) acc[m][n] = (f32x4)0.0f;

    for (int kt = 0; kt < CDIM; kt += 64) {
        __syncthreads();
#pragma unroll
        for (int i = 0; i < 4; ++i) {
            int chunk = wave * 4 + i;
            int row = chunk * 8 + srow;
            gld16(y16 + (size_t)(m0 + row) * CDIM + kt + scol, Ash + chunk * 512);
        }
#pragma unroll
        for (int i = 0; i < 2; ++i) {
            int chunk = wave * 2 + i;    // 8 chunks for 64 rows
            int row = chunk * 8 + srow;
            gld16(wp16 + (size_t)(n0 + row) * CDIM + kt + scol, Bsh + chunk * 512);
        }
        __syncthreads();
#pragma unroll
        for (int kk = 0; kk < 2; ++kk) {
            half8 af[4], bf[2];
#pragma unroll
            for (int m = 0; m < 4; ++m)
                af[m] = *(half8*)&Ash[(wm * 64 + m * 16 + lr) * 64 + kk * 32 + lg * 8];
#pragma unroll
            for (int n = 0; n < 2; ++n)
                bf[n] = *(half8*)&Bsh[(wn * 32 + n * 16 + lr) * 64 + kk * 32 + lg * 8];
#pragma unroll
            for (int m = 0; m < 4; ++m)
#pragma unroll
                for (int n = 0; n < 2; ++n)
                    acc[m][n] = __builtin_amdgcn_mfma_f32_16x16x32_f16(af[m], bf[n], acc[m][n], 0, 0, 0);
        }
    }

#pragma unroll
    for (int n = 0; n < 2; ++n) {
        int col = n0 + wn * 32 + n * 16 + lr;
        float bv_ = bp[col];
#pragma unroll
        for (int m = 0; m < 4; ++m) {
#pragma unroll
            for (int i = 0; i < 4; ++i) {
                int mr = m0 + wm * 64 + m * 16 + lg * 4 + i;
                out[(size_t)mr * CDIM + col] = acc[m][n][i] + bv_;
            }
        }
    }
}

// ---------------------------------------------------------------------------
// Flash attention (causal), fp16 in/out, swapped operands.
// q/k/v fp16 [B,H,T,D], q pre-scaled. K staged via global_load_lds (linear);
// V transposed via registers (coalesced fp16 loads); P via per-wave LDS.
// ---------------------------------------------------------------------------
__global__ __launch_bounds__(256) void attn_kernel(
    const _Float16* __restrict__ q, const _Float16* __restrict__ k,
    const _Float16* __restrict__ v, _Float16* __restrict__ y)
{
    __shared__ _Float16 Kt[64 * 64];         // [kv][d] linear (gld16 dest)
    __shared__ _Float16 Vt[64 * LDH];        // [d][kv] transposed, padded
    __shared__ _Float16 Pt[4][32 * LDH];     // per-wave [q][kv]

    const int tid  = threadIdx.x;
    const int lane = tid & 63;
    const int wave = tid >> 6;
    const int lg = lane >> 4;
    const int lr = lane & 15;

    const int qt  = gridDim.x - 1 - blockIdx.x;   // heavy tiles first
    const int bh  = blockIdx.y;
    const int q0  = qt * 128;
    const int q0w = q0 + wave * 32;

    const _Float16* qb = q + (size_t)bh * SEQ * HD;
    const _Float16* kb = k + (size_t)bh * SEQ * HD;
    const _Float16* vb = v + (size_t)bh * SEQ * HD;

    // Q fragments (B-operand layout) straight from global (pre-scaled fp16)
    half8 qfr[2][2];
#pragma unroll
    for (int f = 0; f < 2; ++f)
#pragma unroll
        for (int kk = 0; kk < 2; ++kk)
            qfr[f][kk] = *(const half8*)(qb + (size_t)(q0w + f * 16 + lr) * HD + kk * 32 + lg * 8);

    f32x4 ot[4][2];
#pragma unroll
    for (int df = 0; df < 4; ++df)
#pragma unroll
        for (int qf = 0; qf < 2; ++qf) ot[df][qf] = (f32x4)0.0f;
    float m_i[2] = {-INFINITY, -INFINITY};
    float l_i[2] = {0.0f, 0.0f};

    // V-transpose thread mapping: coalesced loads (lanes sweep d), unique
    // 4x4 output block per thread.
    const int vd0  = (tid & 15) * 4;
    const int vkv0 = (tid >> 4) * 4;

    const int ntiles = 2 * qt + 2;
    for (int kt = 0; kt < ntiles; ++kt) {
        const int k0 = kt * 64;
        __syncthreads();                 // prior tile's reads done
        // Stage K [kv][d] via async 16B global->LDS (8 x 1KB chunks)
#pragma unroll
        for (int i = 0; i < 2; ++i) {
            int chunk = wave * 2 + i;
            int row = chunk * 8 + (lane >> 3);
            gld16(kb + (size_t)(k0 + row) * HD + (lane & 7) * 8, Kt + chunk * 512);
        }
        // Stage V transposed [d][kv] via 4x4 register blocks (fp16)
        {
            half4 r0 = *(const half4*)(vb + (size_t)(k0 + vkv0 + 0) * HD + vd0);
            half4 r1 = *(const half4*)(vb + (size_t)(k0 + vkv0 + 1) * HD + vd0);
            half4 r2 = *(const half4*)(vb + (size_t)(k0 + vkv0 + 2) * HD + vd0);
            half4 r3 = *(const half4*)(vb + (size_t)(k0 + vkv0 + 3) * HD + vd0);
            half4 c;
#pragma unroll
            for (int j = 0; j < 4; ++j) {
                c[0] = r0[j]; c[1] = r1[j]; c[2] = r2[j]; c[3] = r3[j];
                *(half4*)&Vt[(vd0 + j) * LDH + vkv0] = c;
            }
        }
        __syncthreads();                 // drains vmcnt (K) + lgkm (V)

        // S^T = K · Q^T
        f32x4 st[4][2];
#pragma unroll
        for (int mf = 0; mf < 4; ++mf)
#pragma unroll
            for (int qf = 0; qf < 2; ++qf) st[mf][qf] = (f32x4)0.0f;
#pragma unroll
        for (int kk = 0; kk < 2; ++kk) {
#pragma unroll
            for (int mf = 0; mf < 4; ++mf) {
                half8 ak = *(half8*)&Kt[(mf * 16 + lr) * 64 + kk * 32 + lg * 8];
#pragma unroll
                for (int qf = 0; qf < 2; ++qf)
                    st[mf][qf] = __builtin_amdgcn_mfma_f32_16x16x32_f16(ak, qfr[qf][kk], st[mf][qf], 0, 0, 0);
            }
        }

        // Causal mask
        if (k0 + 63 > q0w) {
#pragma unroll
            for (int mf = 0; mf < 4; ++mf)
#pragma unroll
                for (int qf = 0; qf < 2; ++qf)
#pragma unroll
                    for (int i = 0; i < 4; ++i) {
                        int kv = k0 + mf * 16 + lg * 4 + i;
                        int qq = q0w + qf * 16 + lr;
                        if (kv > qq) st[mf][qf][i] = -INFINITY;
                    }
        }

        // Online softmax + P^T into per-wave LDS
#pragma unroll
        for (int qf = 0; qf < 2; ++qf) {
            float mx = -INFINITY;
#pragma unroll
            for (int mf = 0; mf < 4; ++mf)
#pragma unroll
                for (int i = 0; i < 4; ++i) mx = fmaxf(mx, st[mf][qf][i]);
            mx = fmaxf(mx, __shfl_xor(mx, 16));
            mx = fmaxf(mx, __shfl_xor(mx, 32));
            float nm = fmaxf(m_i[qf], mx);
            float sc = __expf(m_i[qf] - nm);
            m_i[qf] = nm;
            float rs = 0.0f;
#pragma unroll
            for (int mf = 0; mf < 4; ++mf) {
                half4 pk;
#pragma unroll
                for (int i = 0; i < 4; ++i) {
                    float p = __expf(st[mf][qf][i] - nm);
                    rs += p;
                    pk[i] = (_Float16)p;
                }
                *(half4*)&Pt[wave][(qf * 16 + lr) * LDH + mf * 16 + lg * 4] = pk;
            }
            rs += __shfl_xor(rs, 16);
            rs += __shfl_xor(rs, 32);
            l_i[qf] = l_i[qf] * sc + rs;
#pragma unroll
            for (int df = 0; df < 4; ++df)
#pragma unroll
                for (int i = 0; i < 4; ++i) ot[df][qf][i] *= sc;
        }

        // O^T += V^T · P^T
#pragma unroll
        for (int kk = 0; kk < 2; ++kk) {
            half8 bp_[2];
#pragma unroll
            for (int qf = 0; qf < 2; ++qf)
                bp_[qf] = *(half8*)&Pt[wave][(qf * 16 + lr) * LDH + kk * 32 + lg * 8];
#pragma unroll
            for (int df = 0; df < 4; ++df) {
                half8 av = *(half8*)&Vt[(df * 16 + lr) * LDH + kk * 32 + lg * 8];
#pragma unroll
                for (int qf = 0; qf < 2; ++qf)
                    ot[df][qf] = __builtin_amdgcn_mfma_f32_16x16x32_f16(av, bp_[qf], ot[df][qf], 0, 0, 0);
            }
        }
    }

    // Epilogue: normalize, store ybuf fp16 in [B,T,C]
    const int bb = bh >> 4;
    const int h  = bh & 15;
#pragma unroll
    for (int qf = 0; qf < 2; ++qf) {
        float inv = 1.0f / l_i[qf];
        int t = q0w + qf * 16 + lr;
        _Float16* dst = y + ((size_t)(bb * SEQ + t)) * CDIM + h * HD;
#pragma unroll
        for (int df = 0; df < 4; ++df) {
            half4 o4;
#pragma unroll
            for (int i = 0; i < 4; ++i) o4[i] = (_Float16)(ot[df][qf][i] * inv);
            *(half4*)(dst + df * 16 + lg * 4) = o4;
        }
    }
}

extern "C" void kernel_launch(void* const* d_in, const int* in_sizes, int n_in,
                              void* d_out, int out_size, void* d_ws, size_t ws_size,
                              hipStream_t stream) {
    const float* x  = (const float*)d_in[0];
    const float* Wq = (const float*)d_in[1];
    const float* bq = (const float*)d_in[2];
    const float* Wk = (const float*)d_in[3];
    const float* bk = (const float*)d_in[4];
    const float* Wv = (const float*)d_in[5];
    const float* bv = (const float*)d_in[6];
    const float* Wp = (const float*)d_in[7];
    const float* bp = (const float*)d_in[8];
    float* out = (float*)d_out;

    const size_t S = (size_t)BATCH * SEQ * CDIM;   // 4,194,304
    _Float16* ws = (_Float16*)d_ws;
    _Float16* x16  = ws;                  // S halves
    _Float16* w16  = x16 + S;             // 3*CDIM*CDIM = 3,145,728
    _Float16* wp16 = w16 + 3 * CDIM * CDIM;
    _Float16* qbuf = wp16 + CDIM * CDIM;  // S each
    _Float16* kbuf = qbuf + S;
    _Float16* vbuf = kbuf + S;
    _Float16* ybuf = vbuf + S;            // total ~50.3 MB

    cvt_all<<<4096, 256, 0, stream>>>(x, Wq, Wk, Wv, Wp, x16, w16, wp16);

    qkv_gemm<<<dim3(4096 / 128, 3072 / 128), 256, 0, stream>>>(
        x16, w16, bq, bk, bv, qbuf, kbuf, vbuf);

    attn_kernel<<<dim3(SEQ / 128, BATCH * NH), 256, 0, stream>>>(
        qbuf, kbuf, vbuf, ybuf);

    proj_gemm<<<dim3(4096 / 128, 1024 / 64), 256, 0, stream>>>(
        ybuf, wp16, bp, out);
}

// Round 14
// 225.617 us; speedup vs baseline: 4.6519x; 1.0793x over previous
//
#include <hip/hip_runtime.h>
#include <math.h>

#define BATCH 2
#define SEQ   2048
#define CDIM  1024
#define NH    16
#define HD    64

typedef _Float16 half8 __attribute__((ext_vector_type(8)));
typedef _Float16 half4 __attribute__((ext_vector_type(4)));
typedef _Float16 half2v __attribute__((ext_vector_type(2)));
typedef float    f32x4 __attribute__((ext_vector_type(4)));

#define LDH 72   // padded stride (halves) for hand-staged LDS (Vt, Pt)

typedef const __attribute__((address_space(1))) void* gas_ptr;
typedef __attribute__((address_space(3))) void* las_ptr;

// Async global->LDS, 16B per lane: LDS dest = uniform base + lane*16,
// global src per-lane. (guide §5: m97 pattern, width=16)
__device__ __forceinline__ void gld16(const _Float16* g, _Float16* l) {
    __builtin_amdgcn_global_load_lds((gas_ptr)g, (las_ptr)l, 16, 0, 0);
}

__device__ inline half8 cvt8(float4 a, float4 b) {
    half8 h;
    h[0] = (_Float16)a.x; h[1] = (_Float16)a.y; h[2] = (_Float16)a.z; h[3] = (_Float16)a.w;
    h[4] = (_Float16)b.x; h[5] = (_Float16)b.y; h[6] = (_Float16)b.z; h[7] = (_Float16)b.w;
    return h;
}

// ---------------------------------------------------------------------------
// One-shot fp32 -> fp16 conversion of x, Wq|Wk|Wv (concat rows), Wp.
// ---------------------------------------------------------------------------
__global__ __launch_bounds__(256) void cvt_all(
    const float* __restrict__ x,
    const float* __restrict__ Wq, const float* __restrict__ Wk,
    const float* __restrict__ Wv, const float* __restrict__ Wp,
    _Float16* __restrict__ x16, _Float16* __restrict__ w16,
    _Float16* __restrict__ wp16)
{
    int c = blockIdx.x * 256 + threadIdx.x;
    const float* src;
    _Float16* dst;
    if (c < 524288) {                       // x: 4,194,304 floats
        src = x + (size_t)c * 8;
        dst = x16 + (size_t)c * 8;
    } else {
        int r = c - 524288;
        int w = r >> 17;                    // 131072 chunks per weight
        size_t off = (size_t)(r & 131071) * 8;
        if (w == 0)      { src = Wq + off; dst = w16 + off; }
        else if (w == 1) { src = Wk + off; dst = w16 + (1u << 20) + off; }
        else if (w == 2) { src = Wv + off; dst = w16 + (2u << 20) + off; }
        else             { src = Wp + off; dst = wp16 + off; }
    }
    float4 a = *(const float4*)src;
    float4 b = *(const float4*)(src + 4);
    *(half8*)dst = cvt8(a, b);
}

// ---------------------------------------------------------------------------
// Fused QKV projection, pure fp16, m97-style staging (unchanged from R8).
// ---------------------------------------------------------------------------
__global__ __launch_bounds__(256) void qkv_gemm(
    const _Float16* __restrict__ x16, const _Float16* __restrict__ w16,
    const float* __restrict__ bq, const float* __restrict__ bk,
    const float* __restrict__ bv,
    _Float16* __restrict__ q, _Float16* __restrict__ k, _Float16* __restrict__ v)
{
    __shared__ _Float16 Ash[128 * 64];
    __shared__ _Float16 Bsh[128 * 64];

    const int tid  = threadIdx.x;
    const int lane = tid & 63;
    const int wave = tid >> 6;
    const int wm = wave >> 1;
    const int wn = wave & 1;
    const int lg = lane >> 4;
    const int lr = lane & 15;

    const int m0 = blockIdx.x * 128;
    const int nG = blockIdx.y * 128;
    const int w  = nG >> 10;

    const int srow = lane >> 3;          // row within 8-row chunk
    const int scol = (lane & 7) * 8;     // halves

    f32x4 acc[4][4];
#pragma unroll
    for (int m = 0; m < 4; ++m)
#pragma unroll
        for (int n = 0; n < 4; ++n) acc[m][n] = (f32x4)0.0f;

    for (int kt = 0; kt < CDIM; kt += 64) {
        __syncthreads();                 // prior reads of Ash/Bsh done
#pragma unroll
        for (int i = 0; i < 4; ++i) {
            int chunk = wave * 4 + i;    // 16 chunks x 1KB per tile
            int row = chunk * 8 + srow;
            gld16(x16 + (size_t)(m0 + row) * CDIM + kt + scol, Ash + chunk * 512);
            gld16(w16 + (size_t)(nG + row) * CDIM + kt + scol, Bsh + chunk * 512);
        }
        __syncthreads();                 // vmcnt(0)+barrier: tiles ready
#pragma unroll
        for (int kk = 0; kk < 2; ++kk) {
            half8 af[4], bf[4];
#pragma unroll
            for (int m = 0; m < 4; ++m)
                af[m] = *(half8*)&Ash[(wm * 64 + m * 16 + lr) * 64 + kk * 32 + lg * 8];
#pragma unroll
            for (int n = 0; n < 4; ++n)
                bf[n] = *(half8*)&Bsh[(wn * 64 + n * 16 + lr) * 64 + kk * 32 + lg * 8];
#pragma unroll
            for (int m = 0; m < 4; ++m)
#pragma unroll
                for (int n = 0; n < 4; ++n)
                    acc[m][n] = __builtin_amdgcn_mfma_f32_16x16x32_f16(af[m], bf[n], acc[m][n], 0, 0, 0);
        }
    }

    const float* bias = (w == 0) ? bq : (w == 1) ? bk : bv;
    _Float16* dst     = (w == 0) ? q  : (w == 1) ? k  : v;
    const float qs    = (w == 0) ? 0.125f : 1.0f;   // fold 1/sqrt(D) into q
    const int n0 = nG & 1023;

#pragma unroll
    for (int n = 0; n < 4; ++n) {
        int col = n0 + wn * 64 + n * 16 + lr;
        float bv_ = bias[col];
        int h = col >> 6, d = col & 63;
#pragma unroll
        for (int m = 0; m < 4; ++m) {
#pragma unroll
            for (int i = 0; i < 4; ++i) {
                int mr = m0 + wm * 64 + m * 16 + lg * 4 + i;
                int bb = mr >> 11;
                int t  = mr & (SEQ - 1);
                dst[((size_t)(bb * NH + h) * SEQ + t) * HD + d] =
                    (_Float16)((acc[m][n][i] + bv_) * qs);
            }
        }
    }
}

// ---------------------------------------------------------------------------
// Output projection (unchanged from R8).
// ---------------------------------------------------------------------------
__global__ __launch_bounds__(256) void proj_gemm(
    const _Float16* __restrict__ y16, const _Float16* __restrict__ wp16,
    const float* __restrict__ bp, float* __restrict__ out)
{
    __shared__ _Float16 Ash[128 * 64];
    __shared__ _Float16 Bsh[64 * 64];

    const int tid  = threadIdx.x;
    const int lane = tid & 63;
    const int wave = tid >> 6;
    const int wm = wave >> 1;
    const int wn = wave & 1;
    const int lg = lane >> 4;
    const int lr = lane & 15;

    const int m0 = blockIdx.x * 128;
    const int n0 = blockIdx.y * 64;

    const int srow = lane >> 3;
    const int scol = (lane & 7) * 8;

    f32x4 acc[4][2];
#pragma unroll
    for (int m = 0; m < 4; ++m)
#pragma unroll
        for (int n = 0; n < 2; ++n) acc[m][n] = (f32x4)0.0f;

    for (int kt = 0; kt < CDIM; kt += 64) {
        __syncthreads();
#pragma unroll
        for (int i = 0; i < 4; ++i) {
            int chunk = wave * 4 + i;
            int row = chunk * 8 + srow;
            gld16(y16 + (size_t)(m0 + row) * CDIM + kt + scol, Ash + chunk * 512);
        }
#pragma unroll
        for (int i = 0; i < 2; ++i) {
            int chunk = wave * 2 + i;    // 8 chunks for 64 rows
            int row = chunk * 8 + srow;
            gld16(wp16 + (size_t)(n0 + row) * CDIM + kt + scol, Bsh + chunk * 512);
        }
        __syncthreads();
#pragma unroll
        for (int kk = 0; kk < 2; ++kk) {
            half8 af[4], bf[2];
#pragma unroll
            for (int m = 0; m < 4; ++m)
                af[m] = *(half8*)&Ash[(wm * 64 + m * 16 + lr) * 64 + kk * 32 + lg * 8];
#pragma unroll
            for (int n = 0; n < 2; ++n)
                bf[n] = *(half8*)&Bsh[(wn * 32 + n * 16 + lr) * 64 + kk * 32 + lg * 8];
#pragma unroll
            for (int m = 0; m < 4; ++m)
#pragma unroll
                for (int n = 0; n < 2; ++n)
                    acc[m][n] = __builtin_amdgcn_mfma_f32_16x16x32_f16(af[m], bf[n], acc[m][n], 0, 0, 0);
        }
    }

#pragma unroll
    for (int n = 0; n < 2; ++n) {
        int col = n0 + wn * 32 + n * 16 + lr;
        float bv_ = bp[col];
#pragma unroll
        for (int m = 0; m < 4; ++m) {
#pragma unroll
            for (int i = 0; i < 4; ++i) {
                int mr = m0 + wm * 64 + m * 16 + lg * 4 + i;
                out[(size_t)mr * CDIM + col] = acc[m][n][i] + bv_;
            }
        }
    }
}

// ---------------------------------------------------------------------------
// Flash attention (causal), fp16, swapped operands. 8 waves x 16 q-rows.
// - 512 threads/block: 2 blocks/CU x 8 waves = 16 waves/CU (occupancy fix)
// - Kt XOR-swizzled both sides (gld16 source unit ^ row&7; read unit ^ row&7)
// - wave-uniform tail skip: wave computes only tiles with k0 <= q0w+15
// ---------------------------------------------------------------------------
__global__ __launch_bounds__(512) void attn_kernel(
    const _Float16* __restrict__ q, const _Float16* __restrict__ k,
    const _Float16* __restrict__ v, _Float16* __restrict__ y)
{
    __shared__ _Float16 Kt[64 * 64];         // [kv][64], swizzled storage
    __shared__ _Float16 Vt[64 * LDH];        // [d][kv] transposed, padded
    __shared__ _Float16 Pt[8][16 * LDH];     // per-wave [q][kv]

    const int tid  = threadIdx.x;
    const int lane = tid & 63;
    const int wave = tid >> 6;               // 0..7
    const int lg = lane >> 4;
    const int lr = lane & 15;

    const int qt  = gridDim.x - 1 - blockIdx.x;   // heavy tiles first
    const int bh  = blockIdx.y;
    const int q0  = qt * 128;
    const int q0w = q0 + wave * 16;

    const _Float16* qb = q + (size_t)bh * SEQ * HD;
    const _Float16* kb = k + (size_t)bh * SEQ * HD;
    const _Float16* vb = v + (size_t)bh * SEQ * HD;

    // Q fragments (B-operand layout) straight from global (pre-scaled fp16)
    half8 qfr[2];
#pragma unroll
    for (int kk = 0; kk < 2; ++kk)
        qfr[kk] = *(const half8*)(qb + (size_t)(q0w + lr) * HD + kk * 32 + lg * 8);

    f32x4 ot[4];
#pragma unroll
    for (int df = 0; df < 4; ++df) ot[df] = (f32x4)0.0f;
    float m_i = -INFINITY;
    float l_i = 0.0f;

    // K staging: one 1KB gld16 chunk per wave; swizzled global source so
    // LDS[row][u] holds K[row][u ^ (row&7)] (u = 16B unit, row&7 = lane>>3).
    const int krow  = wave * 8 + (lane >> 3);
    const int kunit = (lane & 7) ^ (lane >> 3);
    // V transpose mapping: thread -> 4d x 2kv block; loads coalesced over d.
    const int vd0  = (tid & 15) * 4;
    const int vkv0 = (tid >> 4) * 2;

    const int ntiles = 2 * qt + 2;
    for (int kt = 0; kt < ntiles; ++kt) {
        const int k0 = kt * 64;
        __syncthreads();                 // prior tile's reads done
        gld16(kb + (size_t)(k0 + krow) * HD + kunit * 8, Kt + wave * 512);
        {
            half4 r0 = *(const half4*)(vb + (size_t)(k0 + vkv0 + 0) * HD + vd0);
            half4 r1 = *(const half4*)(vb + (size_t)(k0 + vkv0 + 1) * HD + vd0);
#pragma unroll
            for (int j = 0; j < 4; ++j) {
                half2v c2; c2[0] = r0[j]; c2[1] = r1[j];
                *(half2v*)&Vt[(vd0 + j) * LDH + vkv0] = c2;
            }
        }
        __syncthreads();                 // drains vmcnt (K) + lgkm (V)

        if (k0 <= q0w + 15) {            // wave-uniform: skip fully-masked tiles
            // S^T = K · Q^T  (swizzled Kt reads: 2-way banks, free)
            f32x4 st[4];
#pragma unroll
            for (int mf = 0; mf < 4; ++mf) st[mf] = (f32x4)0.0f;
#pragma unroll
            for (int kk = 0; kk < 2; ++kk) {
#pragma unroll
                for (int mf = 0; mf < 4; ++mf) {
                    half8 ak = *(half8*)&Kt[(mf * 16 + lr) * 64 +
                                            (((kk * 4 + lg) ^ (lr & 7)) * 8)];
                    st[mf] = __builtin_amdgcn_mfma_f32_16x16x32_f16(ak, qfr[kk], st[mf], 0, 0, 0);
                }
            }

            // Causal mask
            if (k0 + 63 > q0w) {
#pragma unroll
                for (int mf = 0; mf < 4; ++mf)
#pragma unroll
                    for (int i = 0; i < 4; ++i) {
                        int kv = k0 + mf * 16 + lg * 4 + i;
                        if (kv > q0w + lr) st[mf][i] = -INFINITY;
                    }
            }

            // Online softmax (1 q-state/thread) + P^T into per-wave LDS
            float mx = -INFINITY;
#pragma unroll
            for (int mf = 0; mf < 4; ++mf)
#pragma unroll
                for (int i = 0; i < 4; ++i) mx = fmaxf(mx, st[mf][i]);
            mx = fmaxf(mx, __shfl_xor(mx, 16));
            mx = fmaxf(mx, __shfl_xor(mx, 32));
            float nm = fmaxf(m_i, mx);
            float sc = __expf(m_i - nm);
            m_i = nm;
            float rs = 0.0f;
#pragma unroll
            for (int mf = 0; mf < 4; ++mf) {
                half4 pk;
#pragma unroll
                for (int i = 0; i < 4; ++i) {
                    float p = __expf(st[mf][i] - nm);
                    rs += p;
                    pk[i] = (_Float16)p;
                }
                *(half4*)&Pt[wave][lr * LDH + mf * 16 + lg * 4] = pk;
            }
            rs += __shfl_xor(rs, 16);
            rs += __shfl_xor(rs, 32);
            l_i = l_i * sc + rs;
#pragma unroll
            for (int df = 0; df < 4; ++df)
#pragma unroll
                for (int i = 0; i < 4; ++i) ot[df][i] *= sc;

            // O^T += V^T · P^T
#pragma unroll
            for (int kk = 0; kk < 2; ++kk) {
                half8 bp_ = *(half8*)&Pt[wave][lr * LDH + kk * 32 + lg * 8];
#pragma unroll
                for (int df = 0; df < 4; ++df) {
                    half8 av = *(half8*)&Vt[(df * 16 + lr) * LDH + kk * 32 + lg * 8];
                    ot[df] = __builtin_amdgcn_mfma_f32_16x16x32_f16(av, bp_, ot[df], 0, 0, 0);
                }
            }
        }
    }

    // Epilogue: normalize, store ybuf fp16 in [B,T,C]
    const int bb = bh >> 4;
    const int h  = bh & 15;
    float inv = 1.0f / l_i;
    int t = q0w + lr;
    _Float16* dst = y + ((size_t)(bb * SEQ + t)) * CDIM + h * HD;
#pragma unroll
    for (int df = 0; df < 4; ++df) {
        half4 o4;
#pragma unroll
        for (int i = 0; i < 4; ++i) o4[i] = (_Float16)(ot[df][i] * inv);
        *(half4*)(dst + df * 16 + lg * 4) = o4;
    }
}

extern "C" void kernel_launch(void* const* d_in, const int* in_sizes, int n_in,
                              void* d_out, int out_size, void* d_ws, size_t ws_size,
                              hipStream_t stream) {
    const float* x  = (const float*)d_in[0];
    const float* Wq = (const float*)d_in[1];
    const float* bq = (const float*)d_in[2];
    const float* Wk = (const float*)d_in[3];
    const float* bk = (const float*)d_in[4];
    const float* Wv = (const float*)d_in[5];
    const float* bv = (const float*)d_in[6];
    const float* Wp = (const float*)d_in[7];
    const float* bp = (const float*)d_in[8];
    float* out = (float*)d_out;

    const size_t S = (size_t)BATCH * SEQ * CDIM;   // 4,194,304
    _Float16* ws = (_Float16*)d_ws;
    _Float16* x16  = ws;                  // S halves
    _Float16* w16  = x16 + S;             // 3*CDIM*CDIM = 3,145,728
    _Float16* wp16 = w16 + 3 * CDIM * CDIM;
    _Float16* qbuf = wp16 + CDIM * CDIM;  // S each
    _Float16* kbuf = qbuf + S;
    _Float16* vbuf = kbuf + S;
    _Float16* ybuf = vbuf + S;            // total ~50.3 MB

    cvt_all<<<4096, 256, 0, stream>>>(x, Wq, Wk, Wv, Wp, x16, w16, wp16);

    qkv_gemm<<<dim3(4096 / 128, 3072 / 128), 256, 0, stream>>>(
        x16, w16, bq, bk, bv, qbuf, kbuf, vbuf);

    attn_kernel<<<dim3(SEQ / 128, BATCH * NH), 512, 0, stream>>>(
        qbuf, kbuf, vbuf, ybuf);

    proj_gemm<<<dim3(4096 / 128, 1024 / 64), 256, 0, stream>>>(
        ybuf, wp16, bp, out);
}